// Round 2
// baseline (27852.332 us; speedup 1.0000x reference)
//
#include <hip/hip_runtime.h>
#include <math.h>

constexpr int SEQ_L = 2048;
constexpr int EDIM  = 300;
constexpr int HDIM  = 512;
constexpr int NCLS  = 20;

// ---------------------------------------------------------------------------
// init: zero h double-buffers and barrier state (ws is poisoned 0xAA each call)
// ---------------------------------------------------------------------------
__global__ void init_kernel(float* Hbuf, unsigned int* bar) {
  int tid = threadIdx.x + blockIdx.x * blockDim.x;
  if (tid < 2048) Hbuf[tid] = 0.0f;   // [2 parity][2 dir][512]
  if (tid < 64) bar[tid] = 0u;        // bar[0]=count, bar[32]=sense
}

// ---------------------------------------------------------------------------
// gi = x @ Wih^T + bih for all timesteps, both directions (backward uses
// reversed sequence). grid (SEQ_L/8, 2), block 256. Each block: 8 timesteps.
// ---------------------------------------------------------------------------
__global__ __launch_bounds__(256) void gi_kernel(
    const int* __restrict__ seq, const float* __restrict__ emb,
    const float* __restrict__ Wih_f, const float* __restrict__ bih_f,
    const float* __restrict__ Wih_b, const float* __restrict__ bih_b,
    float* __restrict__ gi_f, float* __restrict__ gi_b) {
  const int d = blockIdx.y;
  const float* Wih = d ? Wih_b : Wih_f;
  const float* bih = d ? bih_b : bih_f;
  float* gi = d ? gi_b : gi_f;
  const int t0 = blockIdx.x * 8;
  const int tid = threadIdx.x;

  __shared__ float xs[8][304];

  // gather 8 embedding rows (300 f32 each = 75 float4 chunks)
  for (int i = tid; i < 8 * 75; i += 256) {
    int tt = i / 75, u = i - tt * 75;
    int t = t0 + tt;
    int s = seq[d ? (SEQ_L - 1 - t) : t];
    const float4* p = reinterpret_cast<const float4*>(emb + (size_t)s * EDIM);
    float4 v = p[u];
    xs[tt][u * 4 + 0] = v.x; xs[tt][u * 4 + 1] = v.y;
    xs[tt][u * 4 + 2] = v.z; xs[tt][u * 4 + 3] = v.w;
  }
  __syncthreads();

  for (int rr = 0; rr < 6; ++rr) {
    int j = rr * 256 + tid;
    const float4* wrow =
        reinterpret_cast<const float4*>(Wih + (size_t)j * EDIM);
    float acc[8];
#pragma unroll
    for (int tt = 0; tt < 8; ++tt) acc[tt] = 0.0f;
    for (int q = 0; q < EDIM / 4; ++q) {
      float4 w = wrow[q];
#pragma unroll
      for (int tt = 0; tt < 8; ++tt)
        acc[tt] += w.x * xs[tt][4 * q] + w.y * xs[tt][4 * q + 1] +
                   w.z * xs[tt][4 * q + 2] + w.w * xs[tt][4 * q + 3];
    }
    float bb = bih[j];
#pragma unroll
    for (int tt = 0; tt < 8; ++tt)
      gi[(size_t)(t0 + tt) * 1536 + j] = acc[tt] + bb;
  }
}

// ---------------------------------------------------------------------------
// Recurrence: 64 WGs x 1024 thr = 1024 waves. Wave (dir, j) owns Whh rows
// j, j+512, j+1024 in registers. One device-scope barrier per step,
// double-buffered h. All 64 WGs are co-resident (64 blocks << 256 CUs).
// ---------------------------------------------------------------------------
__global__ __launch_bounds__(1024) void rnn_kernel(
    const float* __restrict__ Whh_f, const float* __restrict__ bhh_f,
    const float* __restrict__ Whh_b, const float* __restrict__ bhh_b,
    const float* __restrict__ gi_f, const float* __restrict__ gi_b,
    float* Hbuf,          // [2 parity][2 dir][512]
    unsigned int* bar) {  // bar[0]=count, bar[32]=sense
  const int tid  = threadIdx.x;
  const int lane = tid & 63;
  const int w    = (blockIdx.x << 4) + (tid >> 6);  // 0..1023
  const int dir  = w >> 9;
  const int j    = w & 511;

  const float* Whh = dir ? Whh_b : Whh_f;
  const float* bhh = dir ? bhh_b : bhh_f;
  const float* gi  = dir ? gi_b : gi_f;

  // weights: lane covers columns lane*8 .. lane*8+7 of each of 3 rows
  float wr[8], wz[8], wn[8];
  {
    const float4* r0 = reinterpret_cast<const float4*>(Whh + (size_t)j * HDIM);
    const float4* r1 = reinterpret_cast<const float4*>(Whh + (size_t)(j + 512) * HDIM);
    const float4* r2 = reinterpret_cast<const float4*>(Whh + (size_t)(j + 1024) * HDIM);
    float4 a0 = r0[lane * 2], a1 = r0[lane * 2 + 1];
    float4 b0 = r1[lane * 2], b1 = r1[lane * 2 + 1];
    float4 c0 = r2[lane * 2], c1 = r2[lane * 2 + 1];
    wr[0] = a0.x; wr[1] = a0.y; wr[2] = a0.z; wr[3] = a0.w;
    wr[4] = a1.x; wr[5] = a1.y; wr[6] = a1.z; wr[7] = a1.w;
    wz[0] = b0.x; wz[1] = b0.y; wz[2] = b0.z; wz[3] = b0.w;
    wz[4] = b1.x; wz[5] = b1.y; wz[6] = b1.z; wz[7] = b1.w;
    wn[0] = c0.x; wn[1] = c0.y; wn[2] = c0.z; wn[3] = c0.w;
    wn[4] = c1.x; wn[5] = c1.y; wn[6] = c1.z; wn[7] = c1.w;
  }
  const float bhr = bhh[j];
  const float bhz = bhh[j + 512];
  const float bhn = bhh[j + 1024];

  for (int t = 0; t < SEQ_L; ++t) {
    const int p = t & 1;
    const float* hin = Hbuf + p * 1024 + dir * 512;

    float hv[8];
#pragma unroll
    for (int m = 0; m < 8; ++m)
      hv[m] = __hip_atomic_load(hin + lane * 8 + m, __ATOMIC_RELAXED,
                                __HIP_MEMORY_SCOPE_AGENT);

    float ar = 0.f, az = 0.f, an = 0.f;
#pragma unroll
    for (int m = 0; m < 8; ++m) {
      ar += wr[m] * hv[m];
      az += wz[m] * hv[m];
      an += wn[m] * hv[m];
    }
    // h[j] for the z-gate blend: it lives in lane (j>>3), slot (j&7)
    float hj = __shfl(hv[j & 7], j >> 3, 64);
#pragma unroll
    for (int mask = 32; mask >= 1; mask >>= 1) {
      ar += __shfl_xor(ar, mask, 64);
      az += __shfl_xor(az, mask, 64);
      an += __shfl_xor(an, mask, 64);
    }

    const float* git = gi + (size_t)t * 1536;
    float ir = git[j], iz = git[j + 512], inn = git[j + 1024];
    float r = 1.0f / (1.0f + __expf(-(ir + ar + bhr)));
    float z = 1.0f / (1.0f + __expf(-(iz + az + bhz)));
    float n = tanhf(inn + r * (an + bhn));
    float hnew = (1.0f - z) * n + z * hj;

    if (lane == 0)
      __hip_atomic_store(Hbuf + (1 - p) * 1024 + dir * 512 + j, hnew,
                         __ATOMIC_RELEASE, __HIP_MEMORY_SCOPE_AGENT);

    // one device-scope barrier per step (sense = step counter, no reset race)
    __syncthreads();
    if (tid == 0) {
      unsigned int old = __hip_atomic_fetch_add(&bar[0], 1u, __ATOMIC_ACQ_REL,
                                                __HIP_MEMORY_SCOPE_AGENT);
      if (old == 63u) {
        __hip_atomic_store(&bar[0], 0u, __ATOMIC_RELAXED,
                           __HIP_MEMORY_SCOPE_AGENT);
        __hip_atomic_store(&bar[32], (unsigned int)(t + 1), __ATOMIC_RELEASE,
                           __HIP_MEMORY_SCOPE_AGENT);
      } else {
        while (__hip_atomic_load(&bar[32], __ATOMIC_ACQUIRE,
                                 __HIP_MEMORY_SCOPE_AGENT) <
               (unsigned int)(t + 1)) {
          __builtin_amdgcn_s_sleep(2);
        }
      }
    }
    __syncthreads();
  }
}

// ---------------------------------------------------------------------------
// classifier: hid = relu(W1 @ [hf;hb] + b1); logits = W2 @ hid + b2; softmax
// single block, 1024 threads.
// ---------------------------------------------------------------------------
__global__ __launch_bounds__(1024) void cls_kernel(
    const float* __restrict__ Hbuf,  // parity 0: [dir][512]
    const float* __restrict__ W1, const float* __restrict__ b1,
    const float* __restrict__ W2, const float* __restrict__ b2,
    float* __restrict__ out) {
  __shared__ float hcat[1024];
  __shared__ float hid[512];
  __shared__ float logits[NCLS];
  const int tid = threadIdx.x;
  hcat[tid] = Hbuf[tid];  // [hf(512) | hb(512)] — final h lives at parity 0
  __syncthreads();

  const int lane = tid & 63, widx = tid >> 6;
  for (int rr = 0; rr < 32; ++rr) {
    int row = widx * 32 + rr;
    const float4* wrow = reinterpret_cast<const float4*>(W1 + (size_t)row * 1024);
    float acc = 0.0f;
#pragma unroll
    for (int c = 0; c < 4; ++c) {
      int k = c * 256 + lane * 4;
      float4 v = wrow[c * 64 + lane];
      acc += v.x * hcat[k] + v.y * hcat[k + 1] + v.z * hcat[k + 2] +
             v.w * hcat[k + 3];
    }
#pragma unroll
    for (int mask = 32; mask >= 1; mask >>= 1) acc += __shfl_xor(acc, mask, 64);
    if (lane == 0) hid[row] = fmaxf(acc + b1[row], 0.0f);
  }
  __syncthreads();

  if (tid < NCLS) {
    const float4* wrow = reinterpret_cast<const float4*>(W2 + (size_t)tid * 512);
    float acc = 0.0f;
    for (int q = 0; q < 128; ++q) {
      float4 v = wrow[q];
      int k = q * 4;
      acc += v.x * hid[k] + v.y * hid[k + 1] + v.z * hid[k + 2] +
             v.w * hid[k + 3];
    }
    logits[tid] = acc + b2[tid];
  }
  __syncthreads();

  if (tid == 0) {
    float m = -1e30f;
    for (int i = 0; i < NCLS; ++i) m = fmaxf(m, logits[i]);
    float s = 0.0f;
    float e[NCLS];
    for (int i = 0; i < NCLS; ++i) { e[i] = __expf(logits[i] - m); s += e[i]; }
    float inv = 1.0f / s;
    for (int i = 0; i < NCLS; ++i) out[i] = e[i] * inv;
  }
}

// ---------------------------------------------------------------------------
extern "C" void kernel_launch(void* const* d_in, const int* in_sizes, int n_in,
                              void* d_out, int out_size, void* d_ws,
                              size_t ws_size, hipStream_t stream) {
  (void)in_sizes; (void)n_in; (void)out_size; (void)ws_size;
  const int*   seq   = (const int*)d_in[0];
  const float* emb   = (const float*)d_in[1];
  const float* Wih_f = (const float*)d_in[2];
  const float* Whh_f = (const float*)d_in[3];
  const float* bih_f = (const float*)d_in[4];
  const float* bhh_f = (const float*)d_in[5];
  const float* Wih_b = (const float*)d_in[6];
  const float* Whh_b = (const float*)d_in[7];
  const float* bih_b = (const float*)d_in[8];
  const float* bhh_b = (const float*)d_in[9];
  const float* W1    = (const float*)d_in[10];
  const float* b1    = (const float*)d_in[11];
  const float* W2    = (const float*)d_in[12];
  const float* b2    = (const float*)d_in[13];
  float* out = (float*)d_out;

  float* gi_f = (float*)d_ws;                       // 2048*1536 f32
  float* gi_b = gi_f + (size_t)SEQ_L * 1536;        // 2048*1536 f32
  float* Hbuf = gi_b + (size_t)SEQ_L * 1536;        // 2*2*512 f32
  unsigned int* bar = (unsigned int*)(Hbuf + 2048); // 64 u32 (128B-aligned)

  hipLaunchKernelGGL(init_kernel, dim3(2), dim3(1024), 0, stream, Hbuf, bar);
  hipLaunchKernelGGL(gi_kernel, dim3(SEQ_L / 8, 2), dim3(256), 0, stream,
                     seq, emb, Wih_f, bih_f, Wih_b, bih_b, gi_f, gi_b);
  hipLaunchKernelGGL(rnn_kernel, dim3(64), dim3(1024), 0, stream,
                     Whh_f, bhh_f, Whh_b, bhh_b, gi_f, gi_b, Hbuf, bar);
  hipLaunchKernelGGL(cls_kernel, dim3(1), dim3(1024), 0, stream,
                     Hbuf, W1, b1, W2, b2, out);
}

// Round 3
// 10529.111 us; speedup vs baseline: 2.6453x; 2.6453x over previous
//
#include <hip/hip_runtime.h>
#include <math.h>

constexpr int SEQ_L = 2048;
constexpr int EDIM  = 300;
constexpr int NCLS  = 20;
constexpr int FLAG_STRIDE = 32;   // u32 per flag slot (128 B spacing)

// ---------------------------------------------------------------------------
// init: zero h double-buffers and per-wave flags (ws is poisoned 0xAA)
// ---------------------------------------------------------------------------
__global__ void init_kernel(float* Hbuf, unsigned int* flags) {
  int tid = threadIdx.x + blockIdx.x * blockDim.x;
  if (tid < 2048) Hbuf[tid] = 0.0f;              // [2 parity][2 dir][512]
  if (tid < 128 * FLAG_STRIDE) flags[tid] = 0u;  // one line per wave
}

// ---------------------------------------------------------------------------
// gi = x @ Wih^T + bih (+ bhh folded in for r,z gates) for all timesteps,
// both directions. grid (SEQ_L/8, 2), block 256.
// ---------------------------------------------------------------------------
__global__ __launch_bounds__(256) void gi_kernel(
    const int* __restrict__ seq, const float* __restrict__ emb,
    const float* __restrict__ Wih_f, const float* __restrict__ bih_f,
    const float* __restrict__ bhh_f,
    const float* __restrict__ Wih_b, const float* __restrict__ bih_b,
    const float* __restrict__ bhh_b,
    float* __restrict__ gi_f, float* __restrict__ gi_b) {
  const int d = blockIdx.y;
  const float* Wih = d ? Wih_b : Wih_f;
  const float* bih = d ? bih_b : bih_f;
  const float* bhh = d ? bhh_b : bhh_f;
  float* gi = d ? gi_b : gi_f;
  const int t0 = blockIdx.x * 8;
  const int tid = threadIdx.x;

  __shared__ float xs[8][304];

  for (int i = tid; i < 8 * 75; i += 256) {
    int tt = i / 75, u = i - tt * 75;
    int t = t0 + tt;
    int s = seq[d ? (SEQ_L - 1 - t) : t];
    const float4* p = reinterpret_cast<const float4*>(emb + (size_t)s * EDIM);
    float4 v = p[u];
    xs[tt][u * 4 + 0] = v.x; xs[tt][u * 4 + 1] = v.y;
    xs[tt][u * 4 + 2] = v.z; xs[tt][u * 4 + 3] = v.w;
  }
  __syncthreads();

  for (int rr = 0; rr < 6; ++rr) {
    int j = rr * 256 + tid;
    const float4* wrow = reinterpret_cast<const float4*>(Wih + (size_t)j * EDIM);
    float acc[8];
#pragma unroll
    for (int tt = 0; tt < 8; ++tt) acc[tt] = 0.0f;
    for (int q = 0; q < EDIM / 4; ++q) {
      float4 w = wrow[q];
#pragma unroll
      for (int tt = 0; tt < 8; ++tt)
        acc[tt] += w.x * xs[tt][4 * q] + w.y * xs[tt][4 * q + 1] +
                   w.z * xs[tt][4 * q + 2] + w.w * xs[tt][4 * q + 3];
    }
    // fold bih always; fold bhh for r,z gates (j<1024). n-gate keeps bhh
    // inside r*(...) in the recurrence.
    float bb = bih[j] + (j < 1024 ? bhh[j] : 0.0f);
#pragma unroll
    for (int tt = 0; tt < 8; ++tt)
      gi[(size_t)(t0 + tt) * 1536 + j] = acc[tt] + bb;
  }
}

// ---------------------------------------------------------------------------
// Recurrence: 32 WGs x 256 thr = 128 waves. Wave (dir, wj) owns j0=wj*8..+7,
// i.e. 24 rows of Whh (192 weight floats/lane). No barrier: per-wave flags,
// relaxed poll + acquire fence; release fence + flag store after h write.
// ---------------------------------------------------------------------------
__global__ __launch_bounds__(256, 1) void rnn_kernel(
    const float* __restrict__ Whh_f, const float* __restrict__ bhh_f,
    const float* __restrict__ Whh_b, const float* __restrict__ bhh_b,
    const float* __restrict__ gi_f, const float* __restrict__ gi_b,
    float* Hbuf,            // [2 parity][2 dir][512]
    unsigned int* flags) {  // [128][FLAG_STRIDE]
  const int tid  = threadIdx.x;
  const int lane = tid & 63;
  const int wvid = tid >> 6;                  // 0..3 (wave in WG)
  const int wv   = blockIdx.x * 4 + wvid;     // 0..127
  const int dir  = wv >> 6;
  const int wj   = wv & 63;
  const int j0   = wj * 8;

  const float* Whh = dir ? Whh_b : Whh_f;
  const float* bhh = dir ? bhh_b : bhh_f;
  const float* gi  = dir ? gi_b : gi_f;

  __shared__ float part[4][24][68];  // [wave][row][lane(+pad)]

  // weights: lane holds columns lane*8..+7 of 24 rows (3 gates x 8 j)
  float W[3][8][8];
#pragma unroll
  for (int g = 0; g < 3; ++g) {
#pragma unroll
    for (int jj = 0; jj < 8; ++jj) {
      const float4* p = reinterpret_cast<const float4*>(
                            Whh + (size_t)(g * 512 + j0 + jj) * 512) +
                        lane * 2;
      float4 a = p[0], b = p[1];
      W[g][jj][0] = a.x; W[g][jj][1] = a.y; W[g][jj][2] = a.z; W[g][jj][3] = a.w;
      W[g][jj][4] = b.x; W[g][jj][5] = b.y; W[g][jj][6] = b.z; W[g][jj][7] = b.w;
    }
  }
  const int jl = j0 + (lane & 7);
  const float bhn = bhh[1024 + jl];  // n-gate hidden bias (not folded)

  unsigned int* flagp  = flags + (size_t)(dir * 64 + lane) * FLAG_STRIDE;
  unsigned int* myflag = flags + (size_t)wv * FLAG_STRIDE;

  for (int t = 0; t < SEQ_L; ++t) {
    // prefetch gi for this step (independent of h, hides LLC latency)
    const float* git = gi + (size_t)t * 1536;
    float ir  = git[jl];
    float iz  = git[512 + jl];
    float inn = git[1024 + jl];

    // wait until all 64 producer waves of this dir published h_t
    for (;;) {
      unsigned f = __hip_atomic_load(flagp, __ATOMIC_RELAXED,
                                     __HIP_MEMORY_SCOPE_AGENT);
      if (__ballot(f < (unsigned)t) == 0ull) break;
    }
    __builtin_amdgcn_fence(__ATOMIC_ACQUIRE, "agent");

    const int p = t & 1;
    const float* hin = Hbuf + p * 1024 + dir * 512;
    float hv[8];
#pragma unroll
    for (int m = 0; m < 8; ++m)
      hv[m] = __hip_atomic_load(hin + lane * 8 + m, __ATOMIC_RELAXED,
                                __HIP_MEMORY_SCOPE_AGENT);
    float hj = __hip_atomic_load(hin + jl, __ATOMIC_RELAXED,
                                 __HIP_MEMORY_SCOPE_AGENT);

    // 24 per-lane partial dots
    float s[3][8];
#pragma unroll
    for (int g = 0; g < 3; ++g)
#pragma unroll
      for (int jj = 0; jj < 8; ++jj) {
        float a = 0.0f;
#pragma unroll
        for (int m = 0; m < 8; ++m) a += W[g][jj][m] * hv[m];
        s[g][jj] = a;
      }

    // intra-wave LDS transpose-reduce (DS ops are in-order within a wave)
#pragma unroll
    for (int g = 0; g < 3; ++g)
#pragma unroll
      for (int jj = 0; jj < 8; ++jj) part[wvid][g * 8 + jj][lane] = s[g][jj];
    __builtin_amdgcn_wave_barrier();

    int r = lane < 24 ? lane : 0;
    const float4* rowp = reinterpret_cast<const float4*>(&part[wvid][r][0]);
    float4 a4 = rowp[0];
#pragma unroll
    for (int q = 1; q < 16; ++q) {
      float4 v = rowp[q];
      a4.x += v.x; a4.y += v.y; a4.z += v.z; a4.w += v.w;
    }
    float rowsum = (a4.x + a4.y) + (a4.z + a4.w);
    // lane<8: row lane = r-gate, lane+8 = z-gate, lane+16 = n-gate
    float sz = __shfl(rowsum, lane + 8, 64);
    float sn = __shfl(rowsum, lane + 16, 64);
    float sr = rowsum;

    if (lane < 8) {
      float rr = 1.0f / (1.0f + __expf(-(ir + sr)));
      float zz = 1.0f / (1.0f + __expf(-(iz + sz)));
      float nn = tanhf(inn + rr * (sn + bhn));
      float hnew = (1.0f - zz) * nn + zz * hj;
      __hip_atomic_store(Hbuf + (1 - p) * 1024 + dir * 512 + jl, hnew,
                         __ATOMIC_RELAXED, __HIP_MEMORY_SCOPE_AGENT);
    }
    __builtin_amdgcn_fence(__ATOMIC_RELEASE, "agent");
    if (lane == 0)
      __hip_atomic_store(myflag, (unsigned)(t + 1), __ATOMIC_RELAXED,
                         __HIP_MEMORY_SCOPE_AGENT);
  }
}

// ---------------------------------------------------------------------------
// classifier: hid = relu(W1 @ [hf;hb] + b1); logits = W2 @ hid + b2; softmax
// ---------------------------------------------------------------------------
__global__ __launch_bounds__(1024) void cls_kernel(
    const float* __restrict__ Hbuf,  // parity 0: [dir][512]
    const float* __restrict__ W1, const float* __restrict__ b1,
    const float* __restrict__ W2, const float* __restrict__ b2,
    float* __restrict__ out) {
  __shared__ float hcat[1024];
  __shared__ float hid[512];
  __shared__ float logits[NCLS];
  const int tid = threadIdx.x;
  hcat[tid] = Hbuf[tid];
  __syncthreads();

  const int lane = tid & 63, widx = tid >> 6;
  for (int rr = 0; rr < 32; ++rr) {
    int row = widx * 32 + rr;
    const float4* wrow = reinterpret_cast<const float4*>(W1 + (size_t)row * 1024);
    float acc = 0.0f;
#pragma unroll
    for (int c = 0; c < 4; ++c) {
      int k = c * 256 + lane * 4;
      float4 v = wrow[c * 64 + lane];
      acc += v.x * hcat[k] + v.y * hcat[k + 1] + v.z * hcat[k + 2] +
             v.w * hcat[k + 3];
    }
#pragma unroll
    for (int mask = 32; mask >= 1; mask >>= 1) acc += __shfl_xor(acc, mask, 64);
    if (lane == 0) hid[row] = fmaxf(acc + b1[row], 0.0f);
  }
  __syncthreads();

  if (tid < NCLS) {
    const float4* wrow = reinterpret_cast<const float4*>(W2 + (size_t)tid * 512);
    float acc = 0.0f;
    for (int q = 0; q < 128; ++q) {
      float4 v = wrow[q];
      int k = q * 4;
      acc += v.x * hid[k] + v.y * hid[k + 1] + v.z * hid[k + 2] +
             v.w * hid[k + 3];
    }
    logits[tid] = acc + b2[tid];
  }
  __syncthreads();

  if (tid == 0) {
    float m = -1e30f;
    for (int i = 0; i < NCLS; ++i) m = fmaxf(m, logits[i]);
    float s = 0.0f;
    float e[NCLS];
    for (int i = 0; i < NCLS; ++i) { e[i] = __expf(logits[i] - m); s += e[i]; }
    float inv = 1.0f / s;
    for (int i = 0; i < NCLS; ++i) out[i] = e[i] * inv;
  }
}

// ---------------------------------------------------------------------------
extern "C" void kernel_launch(void* const* d_in, const int* in_sizes, int n_in,
                              void* d_out, int out_size, void* d_ws,
                              size_t ws_size, hipStream_t stream) {
  (void)in_sizes; (void)n_in; (void)out_size; (void)ws_size;
  const int*   seq   = (const int*)d_in[0];
  const float* emb   = (const float*)d_in[1];
  const float* Wih_f = (const float*)d_in[2];
  const float* Whh_f = (const float*)d_in[3];
  const float* bih_f = (const float*)d_in[4];
  const float* bhh_f = (const float*)d_in[5];
  const float* Wih_b = (const float*)d_in[6];
  const float* Whh_b = (const float*)d_in[7];
  const float* bih_b = (const float*)d_in[8];
  const float* bhh_b = (const float*)d_in[9];
  const float* W1    = (const float*)d_in[10];
  const float* b1    = (const float*)d_in[11];
  const float* W2    = (const float*)d_in[12];
  const float* b2    = (const float*)d_in[13];
  float* out = (float*)d_out;

  float* gi_f = (float*)d_ws;                        // 2048*1536 f32
  float* gi_b = gi_f + (size_t)SEQ_L * 1536;         // 2048*1536 f32
  float* Hbuf = gi_b + (size_t)SEQ_L * 1536;         // 2*2*512 f32
  unsigned int* flags = (unsigned int*)(Hbuf + 2048);// 128*32 u32

  hipLaunchKernelGGL(init_kernel, dim3(4), dim3(1024), 0, stream, Hbuf, flags);
  hipLaunchKernelGGL(gi_kernel, dim3(SEQ_L / 8, 2), dim3(256), 0, stream,
                     seq, emb, Wih_f, bih_f, bhh_f, Wih_b, bih_b, bhh_b,
                     gi_f, gi_b);
  hipLaunchKernelGGL(rnn_kernel, dim3(32), dim3(256), 0, stream,
                     Whh_f, bhh_f, Whh_b, bhh_b, gi_f, gi_b, Hbuf, flags);
  hipLaunchKernelGGL(cls_kernel, dim3(1), dim3(1024), 0, stream,
                     Hbuf, W1, b1, W2, b2, out);
}

// Round 5
// 8068.378 us; speedup vs baseline: 3.4520x; 1.3050x over previous
//
#include <hip/hip_runtime.h>
#include <math.h>

constexpr int SEQ_L = 2048;
constexpr int EDIM  = 300;
constexpr int NCLS  = 20;
constexpr unsigned SENT = 0xFFA5A5A5u;  // NaN payload: unproducible by finite math

typedef float f32x4 __attribute__((ext_vector_type(4)));

// ---------------------------------------------------------------------------
// init: Hbuf[0] = h_0 = zeros; Hbuf[1..2048] = sentinel. (ws poisoned 0xAA.)
// Hbuf is (SEQ_L+1) x [2 dir][512] f32 = 2049*1024 dwords = 524544 uint4.
// ---------------------------------------------------------------------------
__global__ __launch_bounds__(256) void init_kernel(uint4* H) {
  const int NT = 513 * 256;
  int idx = blockIdx.x * blockDim.x + threadIdx.x;
  const uint4 z = {0u, 0u, 0u, 0u};
  const uint4 s = {SENT, SENT, SENT, SENT};
#pragma unroll
  for (int i = 0; i < 4; ++i) {
    int q = i * NT + idx;
    if (q < 524544) H[q] = (q < 256) ? z : s;
  }
}

// ---------------------------------------------------------------------------
// gi = x @ Wih^T + bih (+ bhh folded for r,z). grid (SEQ_L/8, 2), block 256.
// ---------------------------------------------------------------------------
__global__ __launch_bounds__(256) void gi_kernel(
    const int* __restrict__ seq, const float* __restrict__ emb,
    const float* __restrict__ Wih_f, const float* __restrict__ bih_f,
    const float* __restrict__ bhh_f,
    const float* __restrict__ Wih_b, const float* __restrict__ bih_b,
    const float* __restrict__ bhh_b,
    float* __restrict__ gi_f, float* __restrict__ gi_b) {
  const int d = blockIdx.y;
  const float* Wih = d ? Wih_b : Wih_f;
  const float* bih = d ? bih_b : bih_f;
  const float* bhh = d ? bhh_b : bhh_f;
  float* gi = d ? gi_b : gi_f;
  const int t0 = blockIdx.x * 8;
  const int tid = threadIdx.x;

  __shared__ float xs[8][304];

  for (int i = tid; i < 8 * 75; i += 256) {
    int tt = i / 75, u = i - tt * 75;
    int t = t0 + tt;
    int s = seq[d ? (SEQ_L - 1 - t) : t];
    const float4* p = reinterpret_cast<const float4*>(emb + (size_t)s * EDIM);
    float4 v = p[u];
    xs[tt][u * 4 + 0] = v.x; xs[tt][u * 4 + 1] = v.y;
    xs[tt][u * 4 + 2] = v.z; xs[tt][u * 4 + 3] = v.w;
  }
  __syncthreads();

  for (int rr = 0; rr < 6; ++rr) {
    int j = rr * 256 + tid;
    const float4* wrow = reinterpret_cast<const float4*>(Wih + (size_t)j * EDIM);
    float acc[8];
#pragma unroll
    for (int tt = 0; tt < 8; ++tt) acc[tt] = 0.0f;
    for (int q = 0; q < EDIM / 4; ++q) {
      float4 w = wrow[q];
#pragma unroll
      for (int tt = 0; tt < 8; ++tt)
        acc[tt] += w.x * xs[tt][4 * q] + w.y * xs[tt][4 * q + 1] +
                   w.z * xs[tt][4 * q + 2] + w.w * xs[tt][4 * q + 3];
    }
    float bb = bih[j] + (j < 1024 ? bhh[j] : 0.0f);
#pragma unroll
    for (int tt = 0; tt < 8; ++tt)
      gi[(size_t)(t0 + tt) * 1536 + j] = acc[tt] + bb;
  }
}

// ---------------------------------------------------------------------------
// Recurrence: 32 WGs x 4 waves = 128 waves. Wave (dir, wj) owns j0=wj*8..+7
// (24 Whh rows register-pinned via asm loads). h goes into a write-once
// history Hbuf[t][dir][512]; consumers poll the data itself vs sentinel with
// relaxed agent atomics (round-3-proven primitives). No flags, no fences,
// no WAR hazard. hj is carried in registers (lane p computed it last step).
// ---------------------------------------------------------------------------
__global__ __launch_bounds__(256, 1) void rnn_kernel(
    const float* __restrict__ Whh_f, const float* __restrict__ bhh_f,
    const float* __restrict__ Whh_b, const float* __restrict__ bhh_b,
    const float* __restrict__ gi_f, const float* __restrict__ gi_b,
    float* Hbuf) {  // [SEQ_L+1][2 dir][512]
  const int tid  = threadIdx.x;
  const int lane = tid & 63;
  const int wvid = tid >> 6;                  // 0..3
  const int wv   = blockIdx.x * 4 + wvid;     // 0..127
  const int dir  = wv >> 6;
  const int wj   = wv & 63;
  const int j0   = wj * 8;

  const float* Whh = dir ? Whh_b : Whh_f;
  const float* bhh = dir ? bhh_b : bhh_f;
  const float* gi  = dir ? gi_b : gi_f;

  __shared__ float part[4][24][68];  // [wave][row][lane(+pad)]

  // 24 rows (r = g*8+jj), lane slice of 8 cols -> 48 float4, register-pinned
  // via asm (compiler cannot rematerialize asm outputs -> no scratch spill).
  f32x4 Wv[48];
#pragma unroll
  for (int r = 0; r < 24; ++r) {
    const float* rp =
        Whh + (size_t)((r >> 3) * 512 + j0 + (r & 7)) * 512 + lane * 8;
    asm volatile(
        "global_load_dwordx4 %0, %2, off\n\tglobal_load_dwordx4 %1, %3, off"
        : "=&v"(Wv[2 * r]), "=&v"(Wv[2 * r + 1])
        : "v"(rp), "v"(rp + 4));
  }
  asm volatile("s_waitcnt vmcnt(0)" ::: "memory");

  const int jl = j0 + (lane & 7);
  const float bhn = bhh[1024 + jl];  // n-gate hidden bias (not folded into gi)
  float hprev = 0.0f;                // lanes 0-7: h_t[j0+lane], carried

  for (int t = 0; t < SEQ_L; ++t) {
    // gi prefetch (independent of h; latency hidden under the poll)
    const float* git = gi + (size_t)t * 1536;
    float ir  = git[jl];
    float iz  = git[512 + jl];
    float inn = git[1024 + jl];

    // poll h_t directly: lane's 8 inputs come from one producer wave's
    // single coalesced store; valid when != sentinel.
    const float* hin = Hbuf + (size_t)t * 1024 + dir * 512 + lane * 8;
    float hv[8];
    for (;;) {
      bool ok = true;
#pragma unroll
      for (int m = 0; m < 8; ++m) {
        hv[m] = __hip_atomic_load(hin + m, __ATOMIC_RELAXED,
                                  __HIP_MEMORY_SCOPE_AGENT);
        ok = ok && (__float_as_uint(hv[m]) != SENT);
      }
      if (__ballot(!ok) == 0ull) break;
    }

    // 24 per-lane partial dots
    float s_[24];
#pragma unroll
    for (int r = 0; r < 24; ++r) {
      f32x4 w0 = Wv[2 * r], w1 = Wv[2 * r + 1];
      s_[r] = w0.x * hv[0] + w0.y * hv[1] + w0.z * hv[2] + w0.w * hv[3] +
              w1.x * hv[4] + w1.y * hv[5] + w1.z * hv[6] + w1.w * hv[7];
    }

    // intra-wave LDS transpose-reduce (round-3-proven)
#pragma unroll
    for (int r = 0; r < 24; ++r) part[wvid][r][lane] = s_[r];
    __builtin_amdgcn_wave_barrier();

    int r = lane < 24 ? lane : 0;
    const f32x4* rowp = reinterpret_cast<const f32x4*>(&part[wvid][r][0]);
    f32x4 a4 = rowp[0];
#pragma unroll
    for (int q = 1; q < 16; ++q) a4 += rowp[q];
    float rowsum = (a4.x + a4.y) + (a4.z + a4.w);
    float sz = __shfl(rowsum, lane + 8, 64);
    float sn = __shfl(rowsum, lane + 16, 64);
    float sr = rowsum;

    if (lane < 8) {
      float rr = 1.0f / (1.0f + __expf(-(ir + sr)));
      float zz = 1.0f / (1.0f + __expf(-(iz + sz)));
      float nn = tanhf(inn + rr * (sn + bhn));
      float hnew = (1.0f - zz) * nn + zz * hprev;
      hprev = hnew;
      __hip_atomic_store(Hbuf + (size_t)(t + 1) * 1024 + dir * 512 + jl, hnew,
                         __ATOMIC_RELAXED, __HIP_MEMORY_SCOPE_AGENT);
    }
  }
}

// ---------------------------------------------------------------------------
// classifier: hid = relu(W1 @ [hf;hb] + b1); logits = W2 @ hid + b2; softmax
// ---------------------------------------------------------------------------
__global__ __launch_bounds__(1024) void cls_kernel(
    const float* __restrict__ Hfin,  // Hbuf slot SEQ_L: [dir][512]
    const float* __restrict__ W1, const float* __restrict__ b1,
    const float* __restrict__ W2, const float* __restrict__ b2,
    float* __restrict__ out) {
  __shared__ float hcat[1024];
  __shared__ float hid[512];
  __shared__ float logits[NCLS];
  const int tid = threadIdx.x;
  hcat[tid] = Hfin[tid];
  __syncthreads();

  const int lane = tid & 63, widx = tid >> 6;
  for (int rr = 0; rr < 32; ++rr) {
    int row = widx * 32 + rr;
    const float4* wrow = reinterpret_cast<const float4*>(W1 + (size_t)row * 1024);
    float acc = 0.0f;
#pragma unroll
    for (int c = 0; c < 4; ++c) {
      int k = c * 256 + lane * 4;
      float4 v = wrow[c * 64 + lane];
      acc += v.x * hcat[k] + v.y * hcat[k + 1] + v.z * hcat[k + 2] +
             v.w * hcat[k + 3];
    }
#pragma unroll
    for (int mask = 32; mask >= 1; mask >>= 1) acc += __shfl_xor(acc, mask, 64);
    if (lane == 0) hid[row] = fmaxf(acc + b1[row], 0.0f);
  }
  __syncthreads();

  if (tid < NCLS) {
    const float4* wrow = reinterpret_cast<const float4*>(W2 + (size_t)tid * 512);
    float acc = 0.0f;
    for (int q = 0; q < 128; ++q) {
      float4 v = wrow[q];
      int k = q * 4;
      acc += v.x * hid[k] + v.y * hid[k + 1] + v.z * hid[k + 2] +
             v.w * hid[k + 3];
    }
    logits[tid] = acc + b2[tid];
  }
  __syncthreads();

  if (tid == 0) {
    float m = -1e30f;
    for (int i = 0; i < NCLS; ++i) m = fmaxf(m, logits[i]);
    float s = 0.0f;
    float e[NCLS];
    for (int i = 0; i < NCLS; ++i) { e[i] = __expf(logits[i] - m); s += e[i]; }
    float inv = 1.0f / s;
    for (int i = 0; i < NCLS; ++i) out[i] = e[i] * inv;
  }
}

// ---------------------------------------------------------------------------
extern "C" void kernel_launch(void* const* d_in, const int* in_sizes, int n_in,
                              void* d_out, int out_size, void* d_ws,
                              size_t ws_size, hipStream_t stream) {
  (void)in_sizes; (void)n_in; (void)out_size; (void)ws_size;
  const int*   seq   = (const int*)d_in[0];
  const float* emb   = (const float*)d_in[1];
  const float* Wih_f = (const float*)d_in[2];
  const float* Whh_f = (const float*)d_in[3];
  const float* bih_f = (const float*)d_in[4];
  const float* bhh_f = (const float*)d_in[5];
  const float* Wih_b = (const float*)d_in[6];
  const float* Whh_b = (const float*)d_in[7];
  const float* bih_b = (const float*)d_in[8];
  const float* bhh_b = (const float*)d_in[9];
  const float* W1    = (const float*)d_in[10];
  const float* b1    = (const float*)d_in[11];
  const float* W2    = (const float*)d_in[12];
  const float* b2    = (const float*)d_in[13];
  float* out = (float*)d_out;

  float* gi_f = (float*)d_ws;                   // 2048*1536 f32 (12.6 MB)
  float* gi_b = gi_f + (size_t)SEQ_L * 1536;    // 12.6 MB
  float* Hbuf = gi_b + (size_t)SEQ_L * 1536;    // 2049*1024 f32 (8.4 MB)

  hipLaunchKernelGGL(init_kernel, dim3(513), dim3(256), 0, stream,
                     (uint4*)Hbuf);
  hipLaunchKernelGGL(gi_kernel, dim3(SEQ_L / 8, 2), dim3(256), 0, stream,
                     seq, emb, Wih_f, bih_f, bhh_f, Wih_b, bih_b, bhh_b,
                     gi_f, gi_b);
  hipLaunchKernelGGL(rnn_kernel, dim3(32), dim3(256), 0, stream,
                     Whh_f, bhh_f, Whh_b, bhh_b, gi_f, gi_b, Hbuf);
  hipLaunchKernelGGL(cls_kernel, dim3(1), dim3(1024), 0, stream,
                     Hbuf + (size_t)SEQ_L * 1024, W1, b1, W2, b2, out);
}

// Round 6
// 4111.105 us; speedup vs baseline: 6.7749x; 1.9626x over previous
//
#include <hip/hip_runtime.h>
#include <math.h>

constexpr int SEQ_L = 2048;
constexpr int EDIM  = 300;
constexpr int NCLS  = 20;
constexpr unsigned SENT = 0xFFA5A5A5u;  // NaN payload: unproducible by finite math

typedef float f32x4 __attribute__((ext_vector_type(4)));

// ---------------------------------------------------------------------------
// init: Hbuf[0] = h_0 = zeros; Hbuf[1..2048] = sentinel. (ws poisoned 0xAA.)
// Hbuf is (SEQ_L+1) x [2 dir][512] f32 = 2049*1024 dwords = 524544 uint4.
// ---------------------------------------------------------------------------
__global__ __launch_bounds__(256) void init_kernel(uint4* H) {
  const int NT = 513 * 256;
  int idx = blockIdx.x * blockDim.x + threadIdx.x;
  const uint4 z = {0u, 0u, 0u, 0u};
  const uint4 s = {SENT, SENT, SENT, SENT};
#pragma unroll
  for (int i = 0; i < 4; ++i) {
    int q = i * NT + idx;
    if (q < 524544) H[q] = (q < 256) ? z : s;
  }
}

// ---------------------------------------------------------------------------
// gi = x @ Wih^T + bih (+ bhh folded for r,z). grid (SEQ_L/8, 2), block 256.
// ---------------------------------------------------------------------------
__global__ __launch_bounds__(256) void gi_kernel(
    const int* __restrict__ seq, const float* __restrict__ emb,
    const float* __restrict__ Wih_f, const float* __restrict__ bih_f,
    const float* __restrict__ bhh_f,
    const float* __restrict__ Wih_b, const float* __restrict__ bih_b,
    const float* __restrict__ bhh_b,
    float* __restrict__ gi_f, float* __restrict__ gi_b) {
  const int d = blockIdx.y;
  const float* Wih = d ? Wih_b : Wih_f;
  const float* bih = d ? bih_b : bih_f;
  const float* bhh = d ? bhh_b : bhh_f;
  float* gi = d ? gi_b : gi_f;
  const int t0 = blockIdx.x * 8;
  const int tid = threadIdx.x;

  __shared__ float xs[8][304];

  for (int i = tid; i < 8 * 75; i += 256) {
    int tt = i / 75, u = i - tt * 75;
    int t = t0 + tt;
    int s = seq[d ? (SEQ_L - 1 - t) : t];
    const float4* p = reinterpret_cast<const float4*>(emb + (size_t)s * EDIM);
    float4 v = p[u];
    xs[tt][u * 4 + 0] = v.x; xs[tt][u * 4 + 1] = v.y;
    xs[tt][u * 4 + 2] = v.z; xs[tt][u * 4 + 3] = v.w;
  }
  __syncthreads();

  for (int rr = 0; rr < 6; ++rr) {
    int j = rr * 256 + tid;
    const float4* wrow = reinterpret_cast<const float4*>(Wih + (size_t)j * EDIM);
    float acc[8];
#pragma unroll
    for (int tt = 0; tt < 8; ++tt) acc[tt] = 0.0f;
    for (int q = 0; q < EDIM / 4; ++q) {
      float4 w = wrow[q];
#pragma unroll
      for (int tt = 0; tt < 8; ++tt)
        acc[tt] += w.x * xs[tt][4 * q] + w.y * xs[tt][4 * q + 1] +
                   w.z * xs[tt][4 * q + 2] + w.w * xs[tt][4 * q + 3];
    }
    float bb = bih[j] + (j < 1024 ? bhh[j] : 0.0f);
#pragma unroll
    for (int tt = 0; tt < 8; ++tt)
      gi[(size_t)(t0 + tt) * 1536 + j] = acc[tt] + bb;
  }
}

// ---------------------------------------------------------------------------
// Recurrence: 32 WGs x 512 thr (8 waves). WG (dir, b) owns j0=b*32..+31:
// 96 Whh rows; wave w holds 12 rows x 8 cols/lane = 96 floats (24 f32x4),
// genuinely register-resident (~140 VGPR < 256 cap @ 2 waves/SIMD).
// h exchange: wave w polls a 64-float slice of h_t (1 dword/lane) from the
// write-once sentinel history, deposits to LDS; after syncthreads every wave
// reads its fragment. Wave 0 does gate math for all 32 j and issues ONE
// coalesced 128B store. Only proven primitives (relaxed agent atomics).
// ---------------------------------------------------------------------------
__global__ __launch_bounds__(512, 2) void rnn_kernel(
    const float* __restrict__ Whh_f, const float* __restrict__ bhh_f,
    const float* __restrict__ Whh_b, const float* __restrict__ bhh_b,
    const float* __restrict__ gi_f, const float* __restrict__ gi_b,
    float* Hbuf) {  // [SEQ_L+1][2 dir][512]
  const int tid  = threadIdx.x;
  const int lane = tid & 63;
  const int w    = tid >> 6;           // wave 0..7
  const int blk  = blockIdx.x;         // 0..31
  const int dir  = blk >> 4;
  const int j0   = (blk & 15) * 32;    // WG's 32 h-outputs

  const float* Whh = dir ? Whh_b : Whh_f;
  const float* bhh = dir ? bhh_b : bhh_f;
  const float* gi  = dir ? gi_b : gi_f;

  alignas(16) __shared__ float hsh[512];
  alignas(16) __shared__ float part[8][12][68];
  __shared__ float rsum[96];

  // wave w, row r = g*4+jj -> Whh row g*512 + j0 + w*4 + jj; lane cols *8..+7
  f32x4 Wv[24];
#pragma unroll
  for (int g = 0; g < 3; ++g)
#pragma unroll
    for (int jj = 0; jj < 4; ++jj) {
      const f32x4* rp = reinterpret_cast<const f32x4*>(
                            Whh + (size_t)(g * 512 + j0 + w * 4 + jj) * 512) +
                        lane * 2;
      Wv[(g * 4 + jj) * 2]     = rp[0];
      Wv[(g * 4 + jj) * 2 + 1] = rp[1];
    }

  const int jl = j0 + lane;  // meaningful for wave 0, lane<32
  float bhn = 0.0f;
  if (w == 0 && lane < 32) bhn = bhh[1024 + jl];
  float hprev = 0.0f;  // wave 0 lane L carries h_t[j0+L]

  const int pollOff = dir * 512 + w * 64 + lane;

  for (int t = 0; t < SEQ_L; ++t) {
    // gi prefetch (wave 0 only; independent of h, hides under poll)
    float ir = 0.f, iz = 0.f, inn = 0.f;
    if (w == 0 && lane < 32) {
      const float* git = gi + (size_t)t * 1536;
      ir  = git[jl];
      iz  = git[512 + jl];
      inn = git[1024 + jl];
    }

    // poll own 64-float slice of h_t (each dword is its own validity flag)
    const float* hp = Hbuf + (size_t)t * 1024 + pollOff;
    float hvp;
    for (;;) {
      hvp = __hip_atomic_load(hp, __ATOMIC_RELAXED, __HIP_MEMORY_SCOPE_AGENT);
      if (__ballot(__float_as_uint(hvp) == SENT) == 0ull) break;
    }
    hsh[w * 64 + lane] = hvp;
    __syncthreads();  // sync1: full h_t in LDS

    const f32x4* hq = reinterpret_cast<const f32x4*>(&hsh[lane * 8]);
    f32x4 h0 = hq[0], h1 = hq[1];

    float s_[12];
#pragma unroll
    for (int r = 0; r < 12; ++r) {
      f32x4 w0 = Wv[2 * r], w1 = Wv[2 * r + 1];
      s_[r] = w0.x * h0.x + w0.y * h0.y + w0.z * h0.z + w0.w * h0.w +
              w1.x * h1.x + w1.y * h1.y + w1.z * h1.z + w1.w * h1.w;
    }

    // intra-wave LDS transpose-reduce (proven pattern)
#pragma unroll
    for (int r = 0; r < 12; ++r) part[w][r][lane] = s_[r];
    __builtin_amdgcn_wave_barrier();
    if (lane < 12) {
      const f32x4* rowp = reinterpret_cast<const f32x4*>(&part[w][lane][0]);
      f32x4 a4 = rowp[0];
#pragma unroll
      for (int q = 1; q < 16; ++q) a4 += rowp[q];
      rsum[w * 12 + lane] = (a4.x + a4.y) + (a4.z + a4.w);
    }
    __syncthreads();  // sync2: rsum ready; also fences hsh reuse at t+1

    if (w == 0 && lane < 32) {
      int ww = lane >> 2, jj = lane & 3;
      float sr = rsum[ww * 12 + jj];
      float sz = rsum[ww * 12 + 4 + jj];
      float sn = rsum[ww * 12 + 8 + jj];
      float rr = 1.0f / (1.0f + __expf(-(ir + sr)));
      float zz = 1.0f / (1.0f + __expf(-(iz + sz)));
      float nn = tanhf(inn + rr * (sn + bhn));
      float hnew = (1.0f - zz) * nn + zz * hprev;
      hprev = hnew;
      __hip_atomic_store(Hbuf + (size_t)(t + 1) * 1024 + dir * 512 + jl, hnew,
                         __ATOMIC_RELAXED, __HIP_MEMORY_SCOPE_AGENT);
    }
  }
}

// ---------------------------------------------------------------------------
// classifier: hid = relu(W1 @ [hf;hb] + b1); logits = W2 @ hid + b2; softmax
// ---------------------------------------------------------------------------
__global__ __launch_bounds__(1024) void cls_kernel(
    const float* __restrict__ Hfin,  // Hbuf slot SEQ_L: [dir][512]
    const float* __restrict__ W1, const float* __restrict__ b1,
    const float* __restrict__ W2, const float* __restrict__ b2,
    float* __restrict__ out) {
  __shared__ float hcat[1024];
  __shared__ float hid[512];
  __shared__ float logits[NCLS];
  const int tid = threadIdx.x;
  hcat[tid] = Hfin[tid];
  __syncthreads();

  const int lane = tid & 63, widx = tid >> 6;
  for (int rr = 0; rr < 32; ++rr) {
    int row = widx * 32 + rr;
    const float4* wrow = reinterpret_cast<const float4*>(W1 + (size_t)row * 1024);
    float acc = 0.0f;
#pragma unroll
    for (int c = 0; c < 4; ++c) {
      int k = c * 256 + lane * 4;
      float4 v = wrow[c * 64 + lane];
      acc += v.x * hcat[k] + v.y * hcat[k + 1] + v.z * hcat[k + 2] +
             v.w * hcat[k + 3];
    }
#pragma unroll
    for (int mask = 32; mask >= 1; mask >>= 1) acc += __shfl_xor(acc, mask, 64);
    if (lane == 0) hid[row] = fmaxf(acc + b1[row], 0.0f);
  }
  __syncthreads();

  if (tid < NCLS) {
    const float4* wrow = reinterpret_cast<const float4*>(W2 + (size_t)tid * 512);
    float acc = 0.0f;
    for (int q = 0; q < 128; ++q) {
      float4 v = wrow[q];
      int k = q * 4;
      acc += v.x * hid[k] + v.y * hid[k + 1] + v.z * hid[k + 2] +
             v.w * hid[k + 3];
    }
    logits[tid] = acc + b2[tid];
  }
  __syncthreads();

  if (tid == 0) {
    float m = -1e30f;
    for (int i = 0; i < NCLS; ++i) m = fmaxf(m, logits[i]);
    float s = 0.0f;
    float e[NCLS];
    for (int i = 0; i < NCLS; ++i) { e[i] = __expf(logits[i] - m); s += e[i]; }
    float inv = 1.0f / s;
    for (int i = 0; i < NCLS; ++i) out[i] = e[i] * inv;
  }
}

// ---------------------------------------------------------------------------
extern "C" void kernel_launch(void* const* d_in, const int* in_sizes, int n_in,
                              void* d_out, int out_size, void* d_ws,
                              size_t ws_size, hipStream_t stream) {
  (void)in_sizes; (void)n_in; (void)out_size; (void)ws_size;
  const int*   seq   = (const int*)d_in[0];
  const float* emb   = (const float*)d_in[1];
  const float* Wih_f = (const float*)d_in[2];
  const float* Whh_f = (const float*)d_in[3];
  const float* bih_f = (const float*)d_in[4];
  const float* bhh_f = (const float*)d_in[5];
  const float* Wih_b = (const float*)d_in[6];
  const float* Whh_b = (const float*)d_in[7];
  const float* bih_b = (const float*)d_in[8];
  const float* bhh_b = (const float*)d_in[9];
  const float* W1    = (const float*)d_in[10];
  const float* b1    = (const float*)d_in[11];
  const float* W2    = (const float*)d_in[12];
  const float* b2    = (const float*)d_in[13];
  float* out = (float*)d_out;

  float* gi_f = (float*)d_ws;                   // 2048*1536 f32 (12.6 MB)
  float* gi_b = gi_f + (size_t)SEQ_L * 1536;    // 12.6 MB
  float* Hbuf = gi_b + (size_t)SEQ_L * 1536;    // 2049*1024 f32 (8.4 MB)

  hipLaunchKernelGGL(init_kernel, dim3(513), dim3(256), 0, stream,
                     (uint4*)Hbuf);
  hipLaunchKernelGGL(gi_kernel, dim3(SEQ_L / 8, 2), dim3(256), 0, stream,
                     seq, emb, Wih_f, bih_f, bhh_f, Wih_b, bih_b, bhh_b,
                     gi_f, gi_b);
  hipLaunchKernelGGL(rnn_kernel, dim3(32), dim3(512), 0, stream,
                     Whh_f, bhh_f, Whh_b, bhh_b, gi_f, gi_b, Hbuf);
  hipLaunchKernelGGL(cls_kernel, dim3(1), dim3(1024), 0, stream,
                     Hbuf + (size_t)SEQ_L * 1024, W1, b1, W2, b2, out);
}